// Round 1
// baseline (4109.947 us; speedup 1.0000x reference)
//
#include <hip/hip_runtime.h>
#include <hip/hip_bf16.h>

typedef __attribute__((ext_vector_type(8)))  short          bf16x8;
typedef __attribute__((ext_vector_type(4)))  float          f32x4;
typedef __attribute__((ext_vector_type(16))) float          f32x16;
typedef __attribute__((ext_vector_type(8)))  unsigned short us8;

__device__ __forceinline__ unsigned short f2b(float f) {
  union { __hip_bfloat16 h; unsigned short u; } v;
  v.h = __float2bfloat16(f);
  return v.u;
}
__device__ __forceinline__ float b2f(unsigned short u) {
  union { unsigned u; float f; } v; v.u = ((unsigned)u) << 16; return v.f;
}
__device__ __forceinline__ float sigf(float x) {
  return __builtin_amdgcn_rcpf(1.f + __expf(-x));
}
__device__ __forceinline__ float tanhf_(float x) {
  return 2.f * __builtin_amdgcn_rcpf(1.f + __expf(-2.f * x)) - 1.f;
}

// ---------- conversion kernels ----------

// embeds f32 -> bf16, elementwise. 67,108,864 elems, 8/thread.
__global__ __launch_bounds__(256) void conv_e(const float* __restrict__ in,
                                              unsigned short* __restrict__ out) {
  const size_t i = ((size_t)blockIdx.x * 256 + threadIdx.x) * 8;
  const float4 v0 = *(const float4*)(in + i);
  const float4 v1 = *(const float4*)(in + i + 4);
  us8 o;
  o[0]=f2b(v0.x); o[1]=f2b(v0.y); o[2]=f2b(v0.z); o[3]=f2b(v0.w);
  o[4]=f2b(v1.x); o[5]=f2b(v1.y); o[6]=f2b(v1.z); o[7]=f2b(v1.w);
  *(us8*)(out + i) = o;
}

// W_x [1024][4096] f32 -> WxT [4096][1024] bf16 (transpose via LDS tile).
__global__ __launch_bounds__(256) void conv_wT(const float* __restrict__ W,
                                               unsigned short* __restrict__ WT) {
  __shared__ float tile[64][65];
  const int bx = blockIdx.x & 63;   // col tile of 4096
  const int by = blockIdx.x >> 6;   // row tile of 1024 (16)
  const int tc = threadIdx.x & 63, tr = threadIdx.x >> 6;
  #pragma unroll
  for (int i = 0; i < 16; ++i) {
    const int r = i * 4 + tr;
    tile[r][tc] = W[(size_t)(by * 64 + r) * 4096 + bx * 64 + tc];
  }
  __syncthreads();
  #pragma unroll
  for (int i = 0; i < 16; ++i) {
    const int c = i * 4 + tr;
    WT[(size_t)(bx * 64 + c) * 1024 + by * 64 + tc] = f2b(tile[tc][c]);
  }
}

// W_h [1024][4096] f32 -> packed bf16 MFMA-B fragments:
// frag id = ((np*2+nt)*64 + kg), lane l holds B[k=kg*16+(l>>5)*8+j][zl=nt*32+(l&31)]
// where zcol = (zl>>4)*1024 + np*16 + (zl&15)  (gate-major 4H layout).
__global__ __launch_bounds__(256) void conv_whp(const float* __restrict__ Wh,
                                                unsigned short* __restrict__ Wp) {
  const int id = blockIdx.x * 256 + threadIdx.x;   // 524288 total
  const int l  = id & 63;
  const int kg = (id >> 6) & 63;
  const int nt = (id >> 12) & 1;
  const int np = id >> 13;
  const int zl = nt * 32 + (l & 31);
  const int col = (zl >> 4) * 1024 + np * 16 + (zl & 15);
  const int k0 = kg * 16 + (l >> 5) * 8;
  us8 o;
  #pragma unroll
  for (int j = 0; j < 8; ++j) o[j] = f2b(Wh[(size_t)(k0 + j) * 4096 + col]);
  *(us8*)(Wp + (size_t)id * 8) = o;
}

// ---------- xproj GEMM: [65536x1024] @ [1024x4096] -> bf16 C (no bias) ----------
// m97-structure: 128x128 tile, BK=64, 4 waves (2x2), global_load_lds width 16.
__global__ __launch_bounds__(256) void gemm_xproj(const unsigned short* __restrict__ A,
                                                  const unsigned short* __restrict__ B,
                                                  unsigned short* __restrict__ C) {
  __shared__ unsigned short Alds[128 * 64];
  __shared__ unsigned short Blds[128 * 64];
  const int tid = threadIdx.x, lane = tid & 63, wv = tid >> 6;
  const int wm = wv >> 1, wn = wv & 1;
  const int bn = blockIdx.x & 31, bm = blockIdx.x >> 5;
  f32x4 acc[4][4] = {};
  const int srow = wv * 8 + (lane >> 3);   // staging row within 32-row group
  const int sinner = (lane & 7) * 8;       // elems within 64-elem row chunk
  for (int kt = 0; kt < 16; ++kt) {
    #pragma unroll
    for (int rd = 0; rd < 4; ++rd) {
      const int row = rd * 32 + srow;
      const unsigned short* ga = A + (size_t)(bm * 128 + row) * 1024 + kt * 64 + sinner;
      const unsigned short* gb = B + (size_t)(bn * 128 + row) * 1024 + kt * 64 + sinner;
      __builtin_amdgcn_global_load_lds(
          (const __attribute__((address_space(1))) unsigned short*)ga,
          (__attribute__((address_space(3))) unsigned short*)(Alds + rd * 2048 + wv * 512),
          16, 0, 0);
      __builtin_amdgcn_global_load_lds(
          (const __attribute__((address_space(1))) unsigned short*)gb,
          (__attribute__((address_space(3))) unsigned short*)(Blds + rd * 2048 + wv * 512),
          16, 0, 0);
    }
    __syncthreads();
    #pragma unroll
    for (int ks = 0; ks < 2; ++ks) {
      const int kk = ks * 32 + (lane >> 4) * 8;
      bf16x8 af[4], bfr[4];
      #pragma unroll
      for (int mt = 0; mt < 4; ++mt)
        af[mt] = *(const bf16x8*)(Alds + (wm * 64 + mt * 16 + (lane & 15)) * 64 + kk);
      #pragma unroll
      for (int nt = 0; nt < 4; ++nt)
        bfr[nt] = *(const bf16x8*)(Blds + (wn * 64 + nt * 16 + (lane & 15)) * 64 + kk);
      #pragma unroll
      for (int mt = 0; mt < 4; ++mt)
        #pragma unroll
        for (int nt = 0; nt < 4; ++nt)
          acc[mt][nt] = __builtin_amdgcn_mfma_f32_16x16x32_bf16(af[mt], bfr[nt], acc[mt][nt], 0, 0, 0);
    }
    __syncthreads();
  }
  #pragma unroll
  for (int mt = 0; mt < 4; ++mt) {
    const int row0 = bm * 128 + wm * 64 + mt * 16 + (lane >> 4) * 4;
    #pragma unroll
    for (int nt = 0; nt < 4; ++nt) {
      const int col = bn * 128 + wn * 64 + nt * 16 + (lane & 15);
      #pragma unroll
      for (int r = 0; r < 4; ++r)
        C[(size_t)(row0 + r) * 4096 + col] = f2b(acc[mt][nt][r]);
    }
  }
}

// ---------- persistent recurrence kernel ----------
// grid 256: block (m = bid>>6 in 0..3 rows-slice of 32, n = bid&63 h-col-slice of 16).
// Per step: z[32x64] = h[32x1024] @ Wh[1024x64(zcols)] via 32x32x16 MFMA,
// K split over 4 waves, LDS reduce, fused cell update, h re-packed for next step.
__global__ __launch_bounds__(256, 1) void lstm_recur(
    const unsigned short* __restrict__ xproj,  // [65536][4096] bf16
    const unsigned short* __restrict__ Wp,     // packed fragments
    const float* __restrict__ bias,            // [4096]
    unsigned short* __restrict__ hbuf,         // [2][131072] packed h fragments
    float* __restrict__ out,                   // [512][128][1024]
    unsigned* __restrict__ sync) {
  __shared__ float zpart[4][32][72];
  const int tid = threadIdx.x;
  const int lane = tid & 63;
  const int wv = tid >> 6;
  const int m = blockIdx.x >> 6;
  const int n = blockIdx.x & 63;
  const int urow = tid >> 3;         // 0..31
  const int uhc = (tid & 7) * 2;     // even h-col within 16
  const int hcol0 = n * 16 + uhc;

  float creg0 = 0.f, creg1 = 0.f;
  unsigned* cntp = sync + m * 64;
  unsigned* genp = sync + m * 64 + 32;

  for (int t = 0; t < 511; ++t) {
    const unsigned short* hsrc = hbuf + (t & 1) * 131072;
    unsigned short* hdst = hbuf + ((t & 1) ^ 1) * 131072;

    f32x16 acc0 = {0.f,0.f,0.f,0.f,0.f,0.f,0.f,0.f,0.f,0.f,0.f,0.f,0.f,0.f,0.f,0.f};
    f32x16 acc1 = {0.f,0.f,0.f,0.f,0.f,0.f,0.f,0.f,0.f,0.f,0.f,0.f,0.f,0.f,0.f,0.f};

    #pragma unroll 4
    for (int ki = 0; ki < 16; ++ki) {
      const int kg = wv * 16 + ki;
      // A fragment: agent-scope (sc0|sc1) loads -> always-fresh h, no cache inv needed
      const unsigned long long* ap =
          (const unsigned long long*)(hsrc + (m * 64 + kg) * 512 + lane * 8);
      union { unsigned long long u[2]; bf16x8 v; } ua;
      ua.u[0] = __hip_atomic_load(ap, __ATOMIC_RELAXED, __HIP_MEMORY_SCOPE_AGENT);
      ua.u[1] = __hip_atomic_load(ap + 1, __ATOMIC_RELAXED, __HIP_MEMORY_SCOPE_AGENT);
      const bf16x8 b0 = *(const bf16x8*)(Wp + ((n * 2 + 0) * 64 + kg) * 512 + lane * 8);
      const bf16x8 b1 = *(const bf16x8*)(Wp + ((n * 2 + 1) * 64 + kg) * 512 + lane * 8);
      acc0 = __builtin_amdgcn_mfma_f32_32x32x16_bf16(ua.v, b0, acc0, 0, 0, 0);
      acc1 = __builtin_amdgcn_mfma_f32_32x32x16_bf16(ua.v, b1, acc1, 0, 0, 0);
    }

    // prefetch xproj for this step (HBM latency hides under LDS phase)
    const size_t xrow = ((size_t)t * 128 + m * 32 + urow) * 4096;
    const unsigned xu0 = *(const unsigned*)(xproj + xrow +        hcol0);
    const unsigned xu1 = *(const unsigned*)(xproj + xrow + 1024 + hcol0);
    const unsigned xu2 = *(const unsigned*)(xproj + xrow + 2048 + hcol0);
    const unsigned xu3 = *(const unsigned*)(xproj + xrow + 3072 + hcol0);

    // dump partial C (32x32 C/D layout: col=lane&31, row=(r&3)+8*(r>>2)+4*(lane>>5))
    #pragma unroll
    for (int r = 0; r < 16; ++r) {
      const int zr = (r & 3) + 8 * (r >> 2) + 4 * (lane >> 5);
      zpart[wv][zr][lane & 31] = acc0[r];
      zpart[wv][zr][32 + (lane & 31)] = acc1[r];
    }
    __syncthreads();

    // cross-wave K reduction: thread owns cells (urow, uhc) and (urow, uhc+1)
    float zc[4][2];
    #pragma unroll
    for (int g = 0; g < 4; ++g)
      #pragma unroll
      for (int j = 0; j < 2; ++j) {
        const int col = g * 16 + uhc + j;
        zc[g][j] = zpart[0][urow][col] + zpart[1][urow][col]
                 + zpart[2][urow][col] + zpart[3][urow][col];
      }

    const float2 bb0 = *(const float2*)(bias +        hcol0);
    const float2 bb1 = *(const float2*)(bias + 1024 + hcol0);
    const float2 bb2 = *(const float2*)(bias + 2048 + hcol0);
    const float2 bb3 = *(const float2*)(bias + 3072 + hcol0);

    float hv0, hv1;
    {
      const float zg = zc[0][0] + b2f((unsigned short)(xu0 & 0xffffu)) + bb0.x;
      const float zi = zc[1][0] + b2f((unsigned short)(xu1 & 0xffffu)) + bb1.x;
      const float zf = zc[2][0] + b2f((unsigned short)(xu2 & 0xffffu)) + bb2.x;
      const float zo = zc[3][0] + b2f((unsigned short)(xu3 & 0xffffu)) + bb3.x;
      creg0 = tanhf_(zg) * sigf(zi) + creg0 * sigf(zf);
      hv0 = tanhf_(creg0) * sigf(zo);
    }
    {
      const float zg = zc[0][1] + b2f((unsigned short)(xu0 >> 16)) + bb0.y;
      const float zi = zc[1][1] + b2f((unsigned short)(xu1 >> 16)) + bb1.y;
      const float zf = zc[2][1] + b2f((unsigned short)(xu2 >> 16)) + bb2.y;
      const float zo = zc[3][1] + b2f((unsigned short)(xu3 >> 16)) + bb3.y;
      creg1 = tanhf_(zg) * sigf(zi) + creg1 * sigf(zf);
      hv1 = tanhf_(creg1) * sigf(zo);
    }

    // out[t+1] = h after step t (reference records h BEFORE update; out[0]=0 via memset)
    float2 ho; ho.x = hv0; ho.y = hv1;
    *(float2*)(out + ((size_t)(t + 1) * 128 + m * 32 + urow) * 1024 + hcol0) = ho;

    // write h bf16 in consumer fragment layout: frag (m, kg=n), lane=(row&31)+32*((col>>3)&1)
    const unsigned hp = (unsigned)f2b(hv0) | ((unsigned)f2b(hv1) << 16);
    unsigned* hd = (unsigned*)(hdst + (m * 64 + n) * 512)
                 + (urow + 32 * (uhc >> 3)) * 4 + ((uhc & 7) >> 1);
    __hip_atomic_store(hd, hp, __ATOMIC_RELAXED, __HIP_MEMORY_SCOPE_AGENT);

    // drain h stores, then per-m-group (64 block) monotonic barrier, all relaxed
    asm volatile("s_waitcnt vmcnt(0)" ::: "memory");
    __syncthreads();
    if (tid == 0) {
      const unsigned a = __hip_atomic_fetch_add(cntp, 1u, __ATOMIC_RELAXED, __HIP_MEMORY_SCOPE_AGENT);
      if (a == (unsigned)(64 * (t + 1) - 1)) {
        __hip_atomic_store(genp, (unsigned)(t + 1), __ATOMIC_RELAXED, __HIP_MEMORY_SCOPE_AGENT);
      } else {
        while (__hip_atomic_load(genp, __ATOMIC_RELAXED, __HIP_MEMORY_SCOPE_AGENT) < (unsigned)(t + 1))
          __builtin_amdgcn_s_sleep(8);
      }
    }
    __syncthreads();
  }
}

extern "C" void kernel_launch(void* const* d_in, const int* in_sizes, int n_in,
                              void* d_out, int out_size, void* d_ws, size_t ws_size,
                              hipStream_t stream) {
  (void)in_sizes; (void)n_in; (void)out_size; (void)ws_size;
  const float* embeds = (const float*)d_in[0];
  const float* Wx     = (const float*)d_in[1];
  const float* Wh     = (const float*)d_in[2];
  const float* bias   = (const float*)d_in[3];
  float* out = (float*)d_out;

  char* w = (char*)d_ws;
  unsigned short* eb  = (unsigned short*)(w);                 // 134,217,728 B
  unsigned short* WxT = (unsigned short*)(w + 134217728);     //   8,388,608 B
  unsigned short* Whp = (unsigned short*)(w + 142606336);     //   8,388,608 B
  unsigned short* xp  = (unsigned short*)(w + 150994944);     // 536,870,912 B
  unsigned short* hb  = (unsigned short*)(w + 687865856);     //     524,288 B
  unsigned*       sy  = (unsigned*)(w + 688390144);           //       1,024 B

  // out[0] = h0 = 0; hbuf[0] = 0; sync counters = 0 (ws is NOT re-poisoned between replays)
  hipMemsetAsync(d_out, 0, (size_t)128 * 1024 * sizeof(float), stream);
  hipMemsetAsync(hb, 0, 262144, stream);
  hipMemsetAsync(sy, 0, 1024, stream);

  conv_e   <<<32768, 256, 0, stream>>>(embeds, eb);
  conv_wT  <<<1024,  256, 0, stream>>>(Wx, WxT);
  conv_whp <<<2048,  256, 0, stream>>>(Wh, Whp);
  gemm_xproj<<<16384, 256, 0, stream>>>(eb, WxT, xp);
  lstm_recur<<<256,   256, 0, stream>>>(xp, Whp, bias, hb, out, sy);
}

// Round 2
// 3565.319 us; speedup vs baseline: 1.1528x; 1.1528x over previous
//
#include <hip/hip_runtime.h>
#include <hip/hip_bf16.h>

typedef __attribute__((ext_vector_type(8)))  short          bf16x8;
typedef __attribute__((ext_vector_type(4)))  float          f32x4;
typedef __attribute__((ext_vector_type(16))) float          f32x16;
typedef __attribute__((ext_vector_type(8)))  unsigned short us8;

__device__ __forceinline__ unsigned short f2b(float f) {
  union { __hip_bfloat16 h; unsigned short u; } v;
  v.h = __float2bfloat16(f);
  return v.u;
}
__device__ __forceinline__ float b2f(unsigned short u) {
  union { unsigned u; float f; } v; v.u = ((unsigned)u) << 16; return v.f;
}
__device__ __forceinline__ float sigf(float x) {
  return __builtin_amdgcn_rcpf(1.f + __expf(-x));
}
__device__ __forceinline__ float tanhf_(float x) {
  return 2.f * __builtin_amdgcn_rcpf(1.f + __expf(-2.f * x)) - 1.f;
}

// ---------- conversion kernels ----------

__global__ __launch_bounds__(256) void conv_e(const float* __restrict__ in,
                                              unsigned short* __restrict__ out) {
  const size_t i = ((size_t)blockIdx.x * 256 + threadIdx.x) * 8;
  const float4 v0 = *(const float4*)(in + i);
  const float4 v1 = *(const float4*)(in + i + 4);
  us8 o;
  o[0]=f2b(v0.x); o[1]=f2b(v0.y); o[2]=f2b(v0.z); o[3]=f2b(v0.w);
  o[4]=f2b(v1.x); o[5]=f2b(v1.y); o[6]=f2b(v1.z); o[7]=f2b(v1.w);
  *(us8*)(out + i) = o;
}

__global__ __launch_bounds__(256) void conv_wT(const float* __restrict__ W,
                                               unsigned short* __restrict__ WT) {
  __shared__ float tile[64][65];
  const int bx = blockIdx.x & 63;
  const int by = blockIdx.x >> 6;
  const int tc = threadIdx.x & 63, tr = threadIdx.x >> 6;
  #pragma unroll
  for (int i = 0; i < 16; ++i) {
    const int r = i * 4 + tr;
    tile[r][tc] = W[(size_t)(by * 64 + r) * 4096 + bx * 64 + tc];
  }
  __syncthreads();
  #pragma unroll
  for (int i = 0; i < 16; ++i) {
    const int c = i * 4 + tr;
    WT[(size_t)(bx * 64 + c) * 1024 + by * 64 + tc] = f2b(tile[tc][c]);
  }
}

// W_h [1024][4096] f32 -> packed bf16 MFMA-B fragments:
// frag id = np*128 + nt*64 + kg; lane l holds B[k=kg*16+(l>>5)*8+j][zl=nt*32+(l&31)]
// where zcol = (zl>>4)*1024 + np*16 + (zl&15)  (gate-major 4H layout).
__global__ __launch_bounds__(256) void conv_whp(const float* __restrict__ Wh,
                                                unsigned short* __restrict__ Wp) {
  const int id = blockIdx.x * 256 + threadIdx.x;   // 524288 total
  const int l  = id & 63;
  const int kg = (id >> 6) & 63;
  const int nt = (id >> 12) & 1;
  const int np = id >> 13;
  const int zl = nt * 32 + (l & 31);
  const int col = (zl >> 4) * 1024 + np * 16 + (zl & 15);
  const int k0 = kg * 16 + (l >> 5) * 8;
  us8 o;
  #pragma unroll
  for (int j = 0; j < 8; ++j) o[j] = f2b(Wh[(size_t)(k0 + j) * 4096 + col]);
  *(us8*)(Wp + (size_t)id * 8) = o;
}

// ---------- xproj GEMM (unchanged, verified) ----------
__global__ __launch_bounds__(256) void gemm_xproj(const unsigned short* __restrict__ A,
                                                  const unsigned short* __restrict__ B,
                                                  unsigned short* __restrict__ C) {
  __shared__ unsigned short Alds[128 * 64];
  __shared__ unsigned short Blds[128 * 64];
  const int tid = threadIdx.x, lane = tid & 63, wv = tid >> 6;
  const int wm = wv >> 1, wn = wv & 1;
  const int bn = blockIdx.x & 31, bm = blockIdx.x >> 5;
  f32x4 acc[4][4] = {};
  const int srow = wv * 8 + (lane >> 3);
  const int sinner = (lane & 7) * 8;
  for (int kt = 0; kt < 16; ++kt) {
    #pragma unroll
    for (int rd = 0; rd < 4; ++rd) {
      const int row = rd * 32 + srow;
      const unsigned short* ga = A + (size_t)(bm * 128 + row) * 1024 + kt * 64 + sinner;
      const unsigned short* gb = B + (size_t)(bn * 128 + row) * 1024 + kt * 64 + sinner;
      __builtin_amdgcn_global_load_lds(
          (const __attribute__((address_space(1))) unsigned short*)ga,
          (__attribute__((address_space(3))) unsigned short*)(Alds + rd * 2048 + wv * 512),
          16, 0, 0);
      __builtin_amdgcn_global_load_lds(
          (const __attribute__((address_space(1))) unsigned short*)gb,
          (__attribute__((address_space(3))) unsigned short*)(Blds + rd * 2048 + wv * 512),
          16, 0, 0);
    }
    __syncthreads();
    #pragma unroll
    for (int ks = 0; ks < 2; ++ks) {
      const int kk = ks * 32 + (lane >> 4) * 8;
      bf16x8 af[4], bfr[4];
      #pragma unroll
      for (int mt = 0; mt < 4; ++mt)
        af[mt] = *(const bf16x8*)(Alds + (wm * 64 + mt * 16 + (lane & 15)) * 64 + kk);
      #pragma unroll
      for (int nt = 0; nt < 4; ++nt)
        bfr[nt] = *(const bf16x8*)(Blds + (wn * 64 + nt * 16 + (lane & 15)) * 64 + kk);
      #pragma unroll
      for (int mt = 0; mt < 4; ++mt)
        #pragma unroll
        for (int nt = 0; nt < 4; ++nt)
          acc[mt][nt] = __builtin_amdgcn_mfma_f32_16x16x32_bf16(af[mt], bfr[nt], acc[mt][nt], 0, 0, 0);
    }
    __syncthreads();
  }
  #pragma unroll
  for (int mt = 0; mt < 4; ++mt) {
    const int row0 = bm * 128 + wm * 64 + mt * 16 + (lane >> 4) * 4;
    #pragma unroll
    for (int nt = 0; nt < 4; ++nt) {
      const int col = bn * 128 + wn * 64 + nt * 16 + (lane & 15);
      #pragma unroll
      for (int r = 0; r < 4; ++r)
        C[(size_t)(row0 + r) * 4096 + col] = f2b(acc[mt][nt][r]);
    }
  }
}

// ---------- persistent recurrence kernel ----------
// grid 256, 1 block/CU (148KB LDS). Block (m = batch slice of 32, n = h-col slice of 16).
// XCD-local remap: m = (bid&7)>>1 so each m-group's 64 blocks sit on 2 XCDs (if round-robin).
// Waves: kh = wv&1 splits K (2x512), nh = wv>>1 splits the 64 z-cols (2x32).
// Wp slice (128KB) lives in LDS; h fragments read via asm dwordx4 sc0 sc1 (coherent);
// barrier = distributed flags + wave-parallel poll (no contended RMW).
__global__ __launch_bounds__(256, 1) void lstm_recur(
    const unsigned short* __restrict__ xproj,  // [65536][4096] bf16
    const unsigned short* __restrict__ Wp,     // packed fragments
    const float* __restrict__ bias,            // [4096]
    unsigned short* __restrict__ hbuf,         // [2][131072] packed h fragments
    float* __restrict__ out,                   // [512][128][1024]
    unsigned* __restrict__ sync) {
  __shared__ unsigned short Wlds[65536];       // 128 frags x 512 shorts = 128KB
  __shared__ float zpart[2][32][67];           // K-half partials, padded
  const int tid = threadIdx.x;
  const int lane = tid & 63;
  const int wv = tid >> 6;
  const int kh = wv & 1;
  const int nh = wv >> 1;
  const int bid = blockIdx.x;
  const int m = (bid & 7) >> 1;
  const int n = ((bid & 1) << 5) | (bid >> 3);
  const int urow = tid >> 3;
  const int uhc = (tid & 7) * 2;
  const int hcol0 = n * 16 + uhc;

  // stage this block's Wp slice (frags [n*128, n*128+128)) into LDS once
  {
    const unsigned short* gw = Wp + (size_t)n * 65536;
    #pragma unroll
    for (int it = 0; it < 32; ++it) {
      const int idx = it * 2048 + tid * 8;
      *(bf16x8*)(Wlds + idx) = *(const bf16x8*)(gw + idx);
    }
  }
  __syncthreads();

  // hoisted bias loads
  const float2 bb0 = *(const float2*)(bias +        hcol0);
  const float2 bb1 = *(const float2*)(bias + 1024 + hcol0);
  const float2 bb2 = *(const float2*)(bias + 2048 + hcol0);
  const float2 bb3 = *(const float2*)(bias + 3072 + hcol0);

  float creg0 = 0.f, creg1 = 0.f;
  unsigned* flg = sync + m * 64;
  const size_t xoff = ((size_t)(m * 32) + urow) * 4096 + hcol0;

  for (int t = 0; t < 511; ++t) {
    const unsigned short* hsrc = hbuf + (t & 1) * 131072;
    unsigned short* hdst = hbuf + ((t & 1) ^ 1) * 131072;
    const unsigned short* abase = hsrc + (m * 64 + kh * 32) * 512 + lane * 8;
    const unsigned short* xpp = xproj + (size_t)t * 524288 + xoff;

    // ---- hand-counted vmem region: only asm loads inside ----
    bf16x8 av[32];
    unsigned xu0, xu1, xu2, xu3;
    __builtin_amdgcn_sched_barrier(0);
    #pragma unroll
    for (int ki = 0; ki < 32; ++ki) {
      asm volatile("global_load_dwordx4 %0, %1, off sc0 sc1"
                   : "=v"(av[ki]) : "v"(abase + ki * 512));
    }
    asm volatile("global_load_dword %0, %1, off" : "=v"(xu0) : "v"(xpp));
    asm volatile("global_load_dword %0, %1, off" : "=v"(xu1) : "v"(xpp + 1024));
    asm volatile("global_load_dword %0, %1, off" : "=v"(xu2) : "v"(xpp + 2048));
    asm volatile("global_load_dword %0, %1, off" : "=v"(xu3) : "v"(xpp + 3072));
    asm volatile("s_waitcnt vmcnt(0)" ::: "memory");
    __builtin_amdgcn_sched_barrier(0);

    // ---- MFMA: z-tile partial for (kh, nh); B from LDS, A from regs ----
    f32x16 accA = {0.f,0.f,0.f,0.f,0.f,0.f,0.f,0.f,0.f,0.f,0.f,0.f,0.f,0.f,0.f,0.f};
    f32x16 accB = {0.f,0.f,0.f,0.f,0.f,0.f,0.f,0.f,0.f,0.f,0.f,0.f,0.f,0.f,0.f,0.f};
    #pragma unroll
    for (int ki = 0; ki < 32; ki += 2) {
      const bf16x8 b0 = *(const bf16x8*)(Wlds + (nh * 64 + kh * 32 + ki) * 512 + lane * 8);
      const bf16x8 b1 = *(const bf16x8*)(Wlds + (nh * 64 + kh * 32 + ki + 1) * 512 + lane * 8);
      accA = __builtin_amdgcn_mfma_f32_32x32x16_bf16(av[ki], b0, accA, 0, 0, 0);
      accB = __builtin_amdgcn_mfma_f32_32x32x16_bf16(av[ki + 1], b1, accB, 0, 0, 0);
    }

    // dump partials (C/D layout: col=lane&31, row=(r&3)+8*(r>>2)+4*(lane>>5))
    #pragma unroll
    for (int r = 0; r < 16; ++r) {
      const int zr = (r & 3) + 8 * (r >> 2) + 4 * (lane >> 5);
      zpart[kh][zr][nh * 32 + (lane & 31)] = accA[r] + accB[r];
    }
    __syncthreads();

    // cross-wave K reduction + activations
    float zc[4][2];
    #pragma unroll
    for (int g = 0; g < 4; ++g)
      #pragma unroll
      for (int j = 0; j < 2; ++j) {
        const int col = g * 16 + uhc + j;
        zc[g][j] = zpart[0][urow][col] + zpart[1][urow][col];
      }

    float hv0, hv1;
    {
      const float zg = zc[0][0] + b2f((unsigned short)(xu0 & 0xffffu)) + bb0.x;
      const float zi = zc[1][0] + b2f((unsigned short)(xu1 & 0xffffu)) + bb1.x;
      const float zf = zc[2][0] + b2f((unsigned short)(xu2 & 0xffffu)) + bb2.x;
      const float zo = zc[3][0] + b2f((unsigned short)(xu3 & 0xffffu)) + bb3.x;
      creg0 = tanhf_(zg) * sigf(zi) + creg0 * sigf(zf);
      hv0 = tanhf_(creg0) * sigf(zo);
    }
    {
      const float zg = zc[0][1] + b2f((unsigned short)(xu0 >> 16)) + bb0.y;
      const float zi = zc[1][1] + b2f((unsigned short)(xu1 >> 16)) + bb1.y;
      const float zf = zc[2][1] + b2f((unsigned short)(xu2 >> 16)) + bb2.y;
      const float zo = zc[3][1] + b2f((unsigned short)(xu3 >> 16)) + bb3.y;
      creg1 = tanhf_(zg) * sigf(zi) + creg1 * sigf(zf);
      hv1 = tanhf_(creg1) * sigf(zo);
    }

    // out[t+1] = h after step t (out[0]=0 via memset)
    float2 ho; ho.x = hv0; ho.y = hv1;
    *(float2*)(out + ((size_t)(t + 1) * 128 + m * 32 + urow) * 1024 + hcol0) = ho;

    // write h bf16 in consumer fragment layout
    const unsigned hp = (unsigned)f2b(hv0) | ((unsigned)f2b(hv1) << 16);
    unsigned* hd = (unsigned*)(hdst + (m * 64 + n) * 512)
                 + (urow + 32 * (uhc >> 3)) * 4 + ((uhc & 7) >> 1);
    __hip_atomic_store(hd, hp, __ATOMIC_RELAXED, __HIP_MEMORY_SCOPE_AGENT);

    if (t < 510) {
      // drain h stores (per-wave), then distributed-flag barrier over the m-group
      asm volatile("s_waitcnt vmcnt(0)" ::: "memory");
      __syncthreads();
      if (tid == 0)
        __hip_atomic_store(flg + n, (unsigned)(t + 1), __ATOMIC_RELAXED, __HIP_MEMORY_SCOPE_AGENT);
      if (tid < 64) {
        unsigned v;
        do {
          __builtin_amdgcn_s_sleep(1);
          v = __hip_atomic_load(flg + tid, __ATOMIC_RELAXED, __HIP_MEMORY_SCOPE_AGENT);
        } while (!__all((int)(v > (unsigned)t)));
      }
      __syncthreads();
    }
  }
}

extern "C" void kernel_launch(void* const* d_in, const int* in_sizes, int n_in,
                              void* d_out, int out_size, void* d_ws, size_t ws_size,
                              hipStream_t stream) {
  (void)in_sizes; (void)n_in; (void)out_size; (void)ws_size;
  const float* embeds = (const float*)d_in[0];
  const float* Wx     = (const float*)d_in[1];
  const float* Wh     = (const float*)d_in[2];
  const float* bias   = (const float*)d_in[3];
  float* out = (float*)d_out;

  char* w = (char*)d_ws;
  unsigned short* eb  = (unsigned short*)(w);                 // 134,217,728 B
  unsigned short* WxT = (unsigned short*)(w + 134217728);     //   8,388,608 B
  unsigned short* Whp = (unsigned short*)(w + 142606336);     //   8,388,608 B
  unsigned short* xp  = (unsigned short*)(w + 150994944);     // 536,870,912 B
  unsigned short* hb  = (unsigned short*)(w + 687865856);     //     524,288 B
  unsigned*       sy  = (unsigned*)(w + 688390144);           //       1,024 B

  hipMemsetAsync(d_out, 0, (size_t)128 * 1024 * sizeof(float), stream);
  hipMemsetAsync(hb, 0, 262144, stream);
  hipMemsetAsync(sy, 0, 1024, stream);

  conv_e   <<<32768, 256, 0, stream>>>(embeds, eb);
  conv_wT  <<<1024,  256, 0, stream>>>(Wx, WxT);
  conv_whp <<<2048,  256, 0, stream>>>(Wh, Whp);
  gemm_xproj<<<16384, 256, 0, stream>>>(eb, WxT, xp);
  lstm_recur<<<256,   256, 0, stream>>>(xp, Whp, bias, hb, out, sy);
}